// Round 1
// baseline (7556.818 us; speedup 1.0000x reference)
//
#include <hip/hip_runtime.h>
#include <math.h>

#define BB 8
#define SS 1024
#define EE 256
#define HH 8
#define DKK 32
#define LL 4
#define FF 1024
#define NQQ 256
#define CC 10

// ---------------------------------------------------------------------------
// Kernel 1: x[b,s,e] = emb[tokens[b,s], e] + pos_encoding(s, e)
// grid = B*S blocks, 256 threads (one per e)
// ---------------------------------------------------------------------------
__global__ void k_embed(const int* __restrict__ tokens,
                        const float* __restrict__ emb,
                        float* __restrict__ x) {
    int bs = blockIdx.x;          // b*S + s
    int e  = threadIdx.x;
    int s  = bs & (SS - 1);
    int tok = tokens[bs];
    // pe: pair index i2 = e/2, div = exp(-(2*i2)*ln(10000)/E)
    int i2 = e >> 1;
    float div = expf(-(float)(2 * i2) * (logf(10000.0f) / (float)EE));
    float ang = (float)s * div;
    float pe = (e & 1) ? cosf(ang) : sinf(ang);
    x[bs * EE + e] = emb[tok * EE + e] + pe;
}

// ---------------------------------------------------------------------------
// Kernel 2: quantum attention projection.
// One thread per (b,s,h): c_j = cos(x_j + theta_j), cumprod; p[0] = prod_{j>=1}
// grid = B*S*H/256 blocks of 256
// ---------------------------------------------------------------------------
__global__ void k_qproj(const float* __restrict__ x,
                        const float* __restrict__ theta,  // [H,DK] for layer l
                        float* __restrict__ p) {
    int idx = blockIdx.x * blockDim.x + threadIdx.x;  // (b*S+s)*H + h
    if (idx >= BB * SS * HH) return;
    int h  = idx & (HH - 1);
    int bs = idx >> 3;
    const float* xr = x + bs * EE + h * DKK;
    const float* th = theta + h * DKK;
    float* pr = p + bs * EE + h * DKK;
    float cum = cosf(xr[0] + th[0]);
    float prod1 = 1.0f;
    #pragma unroll
    for (int j = 1; j < DKK; ++j) {
        float c = cosf(xr[j] + th[j]);
        cum *= c;
        prod1 *= c;
        pr[j] = cum;
    }
    pr[0] = prod1;
}

// ---------------------------------------------------------------------------
// Kernel 3: attention, one block per (b, q). scores in LDS, softmax, PV.
// block = 256 threads
// ---------------------------------------------------------------------------
__global__ void k_attn(const float* __restrict__ p,
                       float* __restrict__ y) {
    int b = blockIdx.x >> 10;       // / S
    int q = blockIdx.x & (SS - 1);
    int t = threadIdx.x;
    __shared__ float pq[EE];
    __shared__ float w[SS];
    __shared__ float red[256];
    const float* pb = p + b * SS * EE;
    pq[t] = pb[q * EE + t];
    __syncthreads();
    const float scale = 0.17677669529663687f;   // 1/sqrt(32)
    float lmax = -1e30f;
    for (int k = t; k < SS; k += 256) {
        const float* pk = pb + k * EE;
        float acc = 0.0f;
        #pragma unroll 8
        for (int e = 0; e < EE; ++e) acc += pq[e] * pk[e];
        acc *= scale;
        w[k] = acc;
        lmax = fmaxf(lmax, acc);
    }
    red[t] = lmax;
    __syncthreads();
    for (int off = 128; off > 0; off >>= 1) {
        if (t < off) red[t] = fmaxf(red[t], red[t + off]);
        __syncthreads();
    }
    float m = red[0];
    __syncthreads();
    float lsum = 0.0f;
    for (int k = t; k < SS; k += 256) {
        float ex = expf(w[k] - m);
        w[k] = ex;
        lsum += ex;
    }
    red[t] = lsum;
    __syncthreads();
    for (int off = 128; off > 0; off >>= 1) {
        if (t < off) red[t] += red[t + off];
        __syncthreads();
    }
    float inv = 1.0f / red[0];
    // PV: out[e] = sum_k w[k] * p[b,k,e]   (coalesced across threads)
    float acc = 0.0f;
    int e = t;
    for (int k = 0; k < SS; ++k) acc += w[k] * pb[k * EE + e];
    y[(b * SS + q) * EE + e] = acc * inv;
}

// ---------------------------------------------------------------------------
// Kernel 4: attn @ Wc + bc, residual add, LayerNorm -> x (in place update)
// one block per token, 256 threads
// ---------------------------------------------------------------------------
__global__ void k_wc_ln(const float* __restrict__ y,
                        const float* __restrict__ Wc,   // [E,E] layer l
                        const float* __restrict__ bc,   // [E]
                        const float* __restrict__ g,
                        const float* __restrict__ bn,
                        float* __restrict__ x) {
    int bs = blockIdx.x;
    int e  = threadIdx.x;
    __shared__ float a[EE];
    __shared__ float red[256];
    a[e] = y[bs * EE + e];
    __syncthreads();
    float acc = bc[e];
    #pragma unroll 8
    for (int k = 0; k < EE; ++k) acc += a[k] * Wc[k * EE + e];
    float v = x[bs * EE + e] + acc;
    // LayerNorm over e
    red[e] = v;
    __syncthreads();
    for (int off = 128; off > 0; off >>= 1) {
        if (e < off) red[e] += red[e + off];
        __syncthreads();
    }
    float mean = red[0] * (1.0f / EE);
    __syncthreads();
    float d = v - mean;
    red[e] = d * d;
    __syncthreads();
    for (int off = 128; off > 0; off >>= 1) {
        if (e < off) red[e] += red[e + off];
        __syncthreads();
    }
    float var = red[0] * (1.0f / EE);
    x[bs * EE + e] = d * rsqrtf(var + 1e-5f) * g[e] + bn[e];
}

// ---------------------------------------------------------------------------
// Kernel 5: FFN fused: q = cos(x)*cos(theta); h = relu(q@W1+b1);
//           out = h@W2 + b2; residual; LN -> x
// one block per token, 256 threads
// ---------------------------------------------------------------------------
__global__ void k_ffn(const float* __restrict__ theta,  // [NQ] layer l
                      const float* __restrict__ W1,     // [NQ,F]
                      const float* __restrict__ b1,     // [F]
                      const float* __restrict__ W2,     // [F,E]
                      const float* __restrict__ b2,     // [E]
                      const float* __restrict__ g,
                      const float* __restrict__ bn,
                      float* __restrict__ x) {
    int bs = blockIdx.x;
    int t  = threadIdx.x;
    __shared__ float qv[NQQ];
    __shared__ float hbuf[FF];
    __shared__ float red[256];
    float xv = x[bs * EE + t];
    qv[t] = cosf(xv) * cosf(theta[t]);
    __syncthreads();
    // h = relu(q @ W1 + b1): each thread owns f = t, t+256, t+512, t+768
    float a0 = b1[t], a1 = b1[t + 256], a2 = b1[t + 512], a3 = b1[t + 768];
    for (int k = 0; k < NQQ; ++k) {
        float qk = qv[k];
        const float* wr = W1 + k * FF + t;
        a0 += qk * wr[0];
        a1 += qk * wr[256];
        a2 += qk * wr[512];
        a3 += qk * wr[768];
    }
    hbuf[t]       = fmaxf(a0, 0.0f);
    hbuf[t + 256] = fmaxf(a1, 0.0f);
    hbuf[t + 512] = fmaxf(a2, 0.0f);
    hbuf[t + 768] = fmaxf(a3, 0.0f);
    __syncthreads();
    int e = t;
    float acc = b2[e];
    #pragma unroll 8
    for (int f = 0; f < FF; ++f) acc += hbuf[f] * W2[f * EE + e];
    float v = xv + acc;
    // LayerNorm
    red[e] = v;
    __syncthreads();
    for (int off = 128; off > 0; off >>= 1) {
        if (e < off) red[e] += red[e + off];
        __syncthreads();
    }
    float mean = red[0] * (1.0f / EE);
    __syncthreads();
    float d = v - mean;
    red[e] = d * d;
    __syncthreads();
    for (int off = 128; off > 0; off >>= 1) {
        if (e < off) red[e] += red[e + off];
        __syncthreads();
    }
    float var = red[0] * (1.0f / EE);
    x[bs * EE + e] = d * rsqrtf(var + 1e-5f) * g[e] + bn[e];
}

// ---------------------------------------------------------------------------
// Kernel 6: out[b,c] = mean_s(x[b,s,:]) @ Wcls + bcls
// one block per b, 256 threads
// ---------------------------------------------------------------------------
__global__ void k_head(const float* __restrict__ x,
                       const float* __restrict__ Wcls,  // [E,C]
                       const float* __restrict__ bcls,  // [C]
                       float* __restrict__ out) {
    int b = blockIdx.x;
    int t = threadIdx.x;
    __shared__ float xm[EE];
    float acc = 0.0f;
    for (int s = 0; s < SS; ++s) acc += x[(b * SS + s) * EE + t];
    xm[t] = acc * (1.0f / (float)SS);
    __syncthreads();
    if (t < CC) {
        float a = bcls[t];
        #pragma unroll 8
        for (int e = 0; e < EE; ++e) a += xm[e] * Wcls[e * CC + t];
        out[b * CC + t] = a;
    }
}

// ---------------------------------------------------------------------------
extern "C" void kernel_launch(void* const* d_in, const int* in_sizes, int n_in,
                              void* d_out, int out_size, void* d_ws, size_t ws_size,
                              hipStream_t stream) {
    (void)in_sizes; (void)n_in; (void)out_size; (void)ws_size;
    const int*   tokens     = (const int*)d_in[0];
    const float* emb        = (const float*)d_in[1];
    const float* theta_attn = (const float*)d_in[2];   // [L,H,DK]
    const float* Wc         = (const float*)d_in[3];   // [L,E,E]
    const float* bc         = (const float*)d_in[4];   // [L,E]
    const float* g1         = (const float*)d_in[5];
    const float* bn1        = (const float*)d_in[6];
    const float* theta_ffn  = (const float*)d_in[7];   // [L,NQ]
    const float* W1         = (const float*)d_in[8];   // [L,NQ,F]
    const float* b1         = (const float*)d_in[9];   // [L,F]
    const float* W2         = (const float*)d_in[10];  // [L,F,E]
    const float* b2         = (const float*)d_in[11];  // [L,E]
    const float* g2         = (const float*)d_in[12];
    const float* bn2        = (const float*)d_in[13];
    const float* Wcls       = (const float*)d_in[14];  // [E,C]
    const float* bcls       = (const float*)d_in[15];  // [C]
    float* out = (float*)d_out;

    // workspace layout: x (8 MB), p (8 MB), y (8 MB)
    const size_t nTok = (size_t)BB * SS * EE;
    float* x = (float*)d_ws;
    float* p = x + nTok;
    float* y = p + nTok;

    k_embed<<<BB * SS, EE, 0, stream>>>(tokens, emb, x);

    for (int l = 0; l < LL; ++l) {
        k_qproj<<<(BB * SS * HH) / 256, 256, 0, stream>>>(
            x, theta_attn + (size_t)l * HH * DKK, p);
        k_attn<<<BB * SS, 256, 0, stream>>>(p, y);
        k_wc_ln<<<BB * SS, EE, 0, stream>>>(
            y, Wc + (size_t)l * EE * EE, bc + (size_t)l * EE,
            g1 + (size_t)l * EE, bn1 + (size_t)l * EE, x);
        k_ffn<<<BB * SS, 256, 0, stream>>>(
            theta_ffn + (size_t)l * NQQ,
            W1 + (size_t)l * NQQ * FF, b1 + (size_t)l * FF,
            W2 + (size_t)l * FF * EE, b2 + (size_t)l * EE,
            g2 + (size_t)l * EE, bn2 + (size_t)l * EE, x);
    }

    k_head<<<BB, 256, 0, stream>>>(x, Wcls, bcls, out);
}

// Round 2
// 2886.480 us; speedup vs baseline: 2.6180x; 2.6180x over previous
//
#include <hip/hip_runtime.h>
#include <math.h>

#define BB 8
#define SS 1024
#define EE 256
#define HH 8
#define DKK 32
#define LL 4
#define FF 1024
#define NQQ 256
#define CC 10

#define QT 32   // queries per attention block
#define KT 32   // key tile
#define TT 16   // tokens per ffn block

// XOR-swizzled LDS offset (word units) for key tiles: row-major [32][256] with
// float4-granularity column swizzle so 16 even (or odd) rows map to 8 distinct
// bank-quads (2-way = free). c must be a multiple of 4.
#define PKOFF(r, c) (((r) << 8) + ((((c) >> 2) ^ (((r) >> 1) & 7)) << 2))

// ---------------------------------------------------------------------------
// Kernel 1: x[b,s,e] = emb[tokens[b,s], e] + pos_encoding(s, e)
// ---------------------------------------------------------------------------
__global__ void k_embed(const int* __restrict__ tokens,
                        const float* __restrict__ emb,
                        float* __restrict__ x) {
    int bs = blockIdx.x;
    int e  = threadIdx.x;
    int s  = bs & (SS - 1);
    int tok = tokens[bs];
    int i2 = e >> 1;
    float div = expf(-(float)(2 * i2) * (logf(10000.0f) / (float)EE));
    float ang = (float)s * div;
    float pe = (e & 1) ? cosf(ang) : sinf(ang);
    x[bs * EE + e] = emb[tok * EE + e] + pe;
}

// ---------------------------------------------------------------------------
// Kernel 2: quantum attention projection (cos-cumprod), 1 thread per (b,s,h)
// ---------------------------------------------------------------------------
__global__ void k_qproj(const float* __restrict__ x,
                        const float* __restrict__ theta,  // [H,DK] layer l
                        float* __restrict__ p) {
    int idx = blockIdx.x * blockDim.x + threadIdx.x;
    if (idx >= BB * SS * HH) return;
    int h  = idx & (HH - 1);
    int bs = idx >> 3;
    const float* xr = x + bs * EE + h * DKK;
    const float* th = theta + h * DKK;
    float* pr = p + bs * EE + h * DKK;
    float cum = cosf(xr[0] + th[0]);
    float prod1 = 1.0f;
    #pragma unroll
    for (int j = 1; j < DKK; ++j) {
        float c = cosf(xr[j] + th[j]);
        cum *= c;
        prod1 *= c;
        pr[j] = cum;
    }
    pr[0] = prod1;
}

// ---------------------------------------------------------------------------
// Kernel 3: flash-style attention, fp32.
// Grid: B * (S/QT) = 256 blocks, 512 threads (8 waves).
// Per block: 32 queries; loop K-tiles of 32 rows staged in LDS.
// Thread roles:
//   scores : q = t>>4 (32 q), kk = t&15 -> keys {2kk, 2kk+1}
//   PV/out : q = t>>4, ei = t&15 -> e in {ei*4 + j*64 : j=0..3}
// ---------------------------------------------------------------------------
__global__ __launch_bounds__(512) void k_attn2(const float* __restrict__ p,
                                               float* __restrict__ y) {
    const int b  = blockIdx.x >> 5;
    const int qt = blockIdx.x & 31;
    const int t  = threadIdx.x;
    __shared__ float pqL[QT * EE];          // linear [32][256]
    __shared__ float pkL[KT * EE];          // swizzled via PKOFF
    __shared__ float w[QT][KT + 1];         // score tile

    const float* pb = p + (size_t)b * SS * EE;
    const int q  = t >> 4;
    const int ei = t & 15;

    // stage pq tile (linear)
    for (int i = t; i < QT * 64; i += 512) {
        int r = i >> 6, c = (i & 63) << 2;
        *(float4*)&pqL[(r << 8) + c] =
            *(const float4*)(pb + (size_t)(qt * QT + r) * EE + c);
    }

    float m = -1e30f, l = 0.0f;
    float acc[4][4];
    #pragma unroll
    for (int j = 0; j < 4; ++j)
        for (int c = 0; c < 4; ++c) acc[j][c] = 0.0f;

    const float scale = 0.17677669529663687f;  // 1/sqrt(32)

    for (int kt = 0; kt < SS / KT; ++kt) {
        // stage pk tile (swizzled)
        for (int i = t; i < KT * 64; i += 512) {
            int r = i >> 6, c = (i & 63) << 2;
            *(float4*)&pkL[PKOFF(r, c)] =
                *(const float4*)(pb + (size_t)(kt * KT + r) * EE + c);
        }
        __syncthreads();

        // scores: each thread computes w[q][2kk], w[q][2kk+1]
        {
            const int kk = ei;
            float s0 = 0.0f, s1 = 0.0f;
            #pragma unroll 4
            for (int e = 0; e < EE; e += 4) {
                float4 a  = *(const float4*)&pqL[(q << 8) + e];
                float4 b0 = *(const float4*)&pkL[PKOFF(2 * kk, e)];
                float4 b1 = *(const float4*)&pkL[PKOFF(2 * kk + 1, e)];
                s0 += a.x * b0.x + a.y * b0.y + a.z * b0.z + a.w * b0.w;
                s1 += a.x * b1.x + a.y * b1.y + a.z * b1.z + a.w * b1.w;
            }
            w[q][2 * kk]     = s0 * scale;
            w[q][2 * kk + 1] = s1 * scale;
        }
        __syncthreads();

        // online softmax + PV
        float tm = -1e30f;
        #pragma unroll
        for (int k = 0; k < KT; ++k) tm = fmaxf(tm, w[q][k]);
        float nm = fmaxf(m, tm);
        float rs = __expf(m - nm);
        m = nm;
        l *= rs;
        #pragma unroll
        for (int j = 0; j < 4; ++j) {
            acc[j][0] *= rs; acc[j][1] *= rs; acc[j][2] *= rs; acc[j][3] *= rs;
        }
        for (int k = 0; k < KT; ++k) {
            float wv = __expf(w[q][k] - m);
            l += wv;
            #pragma unroll
            for (int j = 0; j < 4; ++j) {
                const float4 pv =
                    *(const float4*)&pkL[PKOFF(k, j * 64 + ei * 4)];
                acc[j][0] += wv * pv.x;
                acc[j][1] += wv * pv.y;
                acc[j][2] += wv * pv.z;
                acc[j][3] += wv * pv.w;
            }
        }
        __syncthreads();   // protect pk/w before next tile's staging
    }

    float inv = 1.0f / l;
    float* yr = y + ((size_t)b * SS + qt * QT + q) * EE;
    #pragma unroll
    for (int j = 0; j < 4; ++j) {
        float4 o;
        o.x = acc[j][0] * inv; o.y = acc[j][1] * inv;
        o.z = acc[j][2] * inv; o.w = acc[j][3] * inv;
        *(float4*)(yr + j * 64 + ei * 4) = o;
    }
}

// ---------------------------------------------------------------------------
// Kernel 4: attn @ Wc + bc, residual, LayerNorm (unchanged)
// ---------------------------------------------------------------------------
__global__ void k_wc_ln(const float* __restrict__ y,
                        const float* __restrict__ Wc,
                        const float* __restrict__ bc,
                        const float* __restrict__ g,
                        const float* __restrict__ bn,
                        float* __restrict__ x) {
    int bs = blockIdx.x;
    int e  = threadIdx.x;
    __shared__ float a[EE];
    __shared__ float red[256];
    a[e] = y[bs * EE + e];
    __syncthreads();
    float acc = bc[e];
    #pragma unroll 8
    for (int k = 0; k < EE; ++k) acc += a[k] * Wc[k * EE + e];
    float v = x[bs * EE + e] + acc;
    red[e] = v;
    __syncthreads();
    for (int off = 128; off > 0; off >>= 1) {
        if (e < off) red[e] += red[e + off];
        __syncthreads();
    }
    float mean = red[0] * (1.0f / EE);
    __syncthreads();
    float d = v - mean;
    red[e] = d * d;
    __syncthreads();
    for (int off = 128; off > 0; off >>= 1) {
        if (e < off) red[e] += red[e + off];
        __syncthreads();
    }
    float var = red[0] * (1.0f / EE);
    x[bs * EE + e] = d * rsqrtf(var + 1e-5f) * g[e] + bn[e];
}

// ---------------------------------------------------------------------------
// Kernel 5: FFN, 16 tokens per block, 256 threads, f-chunked (no full hbuf).
// Grid: B*S/TT = 512 blocks.
// ---------------------------------------------------------------------------
__global__ __launch_bounds__(256) void k_ffn2(
        const float* __restrict__ theta,  // [NQ] layer l
        const float* __restrict__ W1,     // [NQ,F]
        const float* __restrict__ b1,     // [F]
        const float* __restrict__ W2,     // [F,E]
        const float* __restrict__ b2,     // [E]
        const float* __restrict__ g,
        const float* __restrict__ bn,
        float* __restrict__ x) {
    const int t = threadIdx.x;
    const size_t base = (size_t)blockIdx.x * TT * EE;
    __shared__ float qv[TT][260];
    __shared__ float hs[TT][68];

    // stage qv = cos(x)*cos(theta)
    for (int i = t; i < TT * 64; i += 256) {
        int r = i >> 6, c = (i & 63) << 2;
        float4 xv = *(const float4*)(x + base + (size_t)r * EE + c);
        float4 th = *(const float4*)(theta + c);
        float4 qq;
        qq.x = cosf(xv.x) * cosf(th.x);
        qq.y = cosf(xv.y) * cosf(th.y);
        qq.z = cosf(xv.z) * cosf(th.z);
        qq.w = cosf(xv.w) * cosf(th.w);
        *(float4*)&qv[r][c] = qq;
    }
    __syncthreads();

    const int eg  = t & 63;   // e = eg*4 (W2 mapping)
    const int wv_ = t >> 6;   // wave id -> tokens wv_*4 .. +3
    float4 oacc[4];
    {
        float4 b2v = *(const float4*)(b2 + eg * 4);
        #pragma unroll
        for (int j = 0; j < 4; ++j) oacc[j] = b2v;
    }

    const int fg = t & 15, tg = t >> 4;  // W1 mapping: token tg, f = fbase+fg*4
    for (int fc = 0; fc < FF / 64; ++fc) {
        const int fbase = fc * 64;
        // h[tg][fbase + fg*4 .. +3]
        float4 a = *(const float4*)(b1 + fbase + fg * 4);
        for (int k = 0; k < EE; k += 4) {
            float4 qk = *(const float4*)&qv[tg][k];
            const float* w1p = W1 + (size_t)k * FF + fbase + fg * 4;
            float4 w10 = *(const float4*)(w1p);
            float4 w11 = *(const float4*)(w1p + FF);
            float4 w12 = *(const float4*)(w1p + 2 * FF);
            float4 w13 = *(const float4*)(w1p + 3 * FF);
            a.x += qk.x * w10.x + qk.y * w11.x + qk.z * w12.x + qk.w * w13.x;
            a.y += qk.x * w10.y + qk.y * w11.y + qk.z * w12.y + qk.w * w13.y;
            a.z += qk.x * w10.z + qk.y * w11.z + qk.z * w12.z + qk.w * w13.z;
            a.w += qk.x * w10.w + qk.y * w11.w + qk.z * w12.w + qk.w * w13.w;
        }
        a.x = fmaxf(a.x, 0.0f);
        a.y = fmaxf(a.y, 0.0f);
        a.z = fmaxf(a.z, 0.0f);
        a.w = fmaxf(a.w, 0.0f);
        *(float4*)&hs[tg][fg * 4] = a;
        __syncthreads();
        // accumulate out[tok][e] += h[tok][f] * W2[f][e]
        #pragma unroll 4
        for (int f4 = 0; f4 < 16; ++f4) {
            int f = fbase + f4 * 4;
            const float* w2p = W2 + (size_t)f * EE + eg * 4;
            float4 w20 = *(const float4*)(w2p);
            float4 w21 = *(const float4*)(w2p + EE);
            float4 w22 = *(const float4*)(w2p + 2 * EE);
            float4 w23 = *(const float4*)(w2p + 3 * EE);
            #pragma unroll
            for (int j = 0; j < 4; ++j) {
                float4 hv = *(const float4*)&hs[wv_ * 4 + j][f4 * 4];
                oacc[j].x += hv.x * w20.x + hv.y * w21.x + hv.z * w22.x + hv.w * w23.x;
                oacc[j].y += hv.x * w20.y + hv.y * w21.y + hv.z * w22.y + hv.w * w23.y;
                oacc[j].z += hv.x * w20.z + hv.y * w21.z + hv.z * w22.z + hv.w * w23.z;
                oacc[j].w += hv.x * w20.w + hv.y * w21.w + hv.z * w22.w + hv.w * w23.w;
            }
        }
        __syncthreads();
    }

    // epilogue: residual + LN per token (wave-local, shfl reduce over 64 lanes)
    float4 gv  = *(const float4*)(g + eg * 4);
    float4 bnv = *(const float4*)(bn + eg * 4);
    #pragma unroll
    for (int j = 0; j < 4; ++j) {
        int tok = wv_ * 4 + j;
        float4 xv = *(const float4*)(x + base + (size_t)tok * EE + eg * 4);
        float4 v;
        v.x = xv.x + oacc[j].x; v.y = xv.y + oacc[j].y;
        v.z = xv.z + oacc[j].z; v.w = xv.w + oacc[j].w;
        float s = v.x + v.y + v.z + v.w;
        for (int off = 32; off > 0; off >>= 1) s += __shfl_xor(s, off);
        float mean = s * (1.0f / EE);
        float4 d;
        d.x = v.x - mean; d.y = v.y - mean; d.z = v.z - mean; d.w = v.w - mean;
        float s2 = d.x * d.x + d.y * d.y + d.z * d.z + d.w * d.w;
        for (int off = 32; off > 0; off >>= 1) s2 += __shfl_xor(s2, off);
        float inv = rsqrtf(s2 * (1.0f / EE) + 1e-5f);
        float4 o;
        o.x = d.x * inv * gv.x + bnv.x;
        o.y = d.y * inv * gv.y + bnv.y;
        o.z = d.z * inv * gv.z + bnv.z;
        o.w = d.w * inv * gv.w + bnv.w;
        *(float4*)(x + base + (size_t)tok * EE + eg * 4) = o;
    }
}

// ---------------------------------------------------------------------------
// Kernel 6: classifier head (unchanged)
// ---------------------------------------------------------------------------
__global__ void k_head(const float* __restrict__ x,
                       const float* __restrict__ Wcls,
                       const float* __restrict__ bcls,
                       float* __restrict__ out) {
    int b = blockIdx.x;
    int t = threadIdx.x;
    __shared__ float xm[EE];
    float acc = 0.0f;
    for (int s = 0; s < SS; ++s) acc += x[(b * SS + s) * EE + t];
    xm[t] = acc * (1.0f / (float)SS);
    __syncthreads();
    if (t < CC) {
        float a = bcls[t];
        #pragma unroll 8
        for (int e = 0; e < EE; ++e) a += xm[e] * Wcls[e * CC + t];
        out[b * CC + t] = a;
    }
}

// ---------------------------------------------------------------------------
extern "C" void kernel_launch(void* const* d_in, const int* in_sizes, int n_in,
                              void* d_out, int out_size, void* d_ws, size_t ws_size,
                              hipStream_t stream) {
    (void)in_sizes; (void)n_in; (void)out_size; (void)ws_size;
    const int*   tokens     = (const int*)d_in[0];
    const float* emb        = (const float*)d_in[1];
    const float* theta_attn = (const float*)d_in[2];
    const float* Wc         = (const float*)d_in[3];
    const float* bc         = (const float*)d_in[4];
    const float* g1         = (const float*)d_in[5];
    const float* bn1        = (const float*)d_in[6];
    const float* theta_ffn  = (const float*)d_in[7];
    const float* W1         = (const float*)d_in[8];
    const float* b1         = (const float*)d_in[9];
    const float* W2         = (const float*)d_in[10];
    const float* b2         = (const float*)d_in[11];
    const float* g2         = (const float*)d_in[12];
    const float* bn2        = (const float*)d_in[13];
    const float* Wcls       = (const float*)d_in[14];
    const float* bcls       = (const float*)d_in[15];
    float* out = (float*)d_out;

    const size_t nTok = (size_t)BB * SS * EE;
    float* x = (float*)d_ws;
    float* p = x + nTok;
    float* y = p + nTok;

    k_embed<<<BB * SS, EE, 0, stream>>>(tokens, emb, x);

    for (int l = 0; l < LL; ++l) {
        k_qproj<<<(BB * SS * HH) / 256, 256, 0, stream>>>(
            x, theta_attn + (size_t)l * HH * DKK, p);
        k_attn2<<<BB * (SS / QT), 512, 0, stream>>>(p, y);
        k_wc_ln<<<BB * SS, EE, 0, stream>>>(
            y, Wc + (size_t)l * EE * EE, bc + (size_t)l * EE,
            g1 + (size_t)l * EE, bn1 + (size_t)l * EE, x);
        k_ffn2<<<(BB * SS) / TT, 256, 0, stream>>>(
            theta_ffn + (size_t)l * NQQ,
            W1 + (size_t)l * NQQ * FF, b1 + (size_t)l * FF,
            W2 + (size_t)l * FF * EE, b2 + (size_t)l * EE,
            g2 + (size_t)l * EE, bn2 + (size_t)l * EE, x);
    }

    k_head<<<BB, 256, 0, stream>>>(x, Wcls, bcls, out);
}

// Round 3
// 825.742 us; speedup vs baseline: 9.1515x; 3.4956x over previous
//
#include <hip/hip_runtime.h>
#include <hip/hip_bf16.h>
#include <math.h>

#define BB 8
#define SS 1024
#define EE 256
#define HH 8
#define DKK 32
#define LL 4
#define FF 1024
#define NQQ 256
#define CC 10

typedef __attribute__((ext_vector_type(8))) short short8;
typedef __attribute__((ext_vector_type(4))) short s16x4;
typedef __attribute__((ext_vector_type(4))) float f32x4;

static __device__ __forceinline__ f32x4 mfma16(short8 a, short8 b, f32x4 c) {
    return __builtin_amdgcn_mfma_f32_16x16x32_bf16(a, b, c, 0, 0, 0);
}
static __device__ __forceinline__ short f2bf(float f) {
    __hip_bfloat16 h = __float2bfloat16(f);
    return *reinterpret_cast<short*>(&h);
}

// ---------------------------------------------------------------------------
// Kernel 1: x[b,s,e] = emb[tokens[b,s], e] + pos_encoding(s, e)  (fp32, exact)
// ---------------------------------------------------------------------------
__global__ void k_embed(const int* __restrict__ tokens,
                        const float* __restrict__ emb,
                        float* __restrict__ x) {
    int bs = blockIdx.x;
    int e  = threadIdx.x;
    int s  = bs & (SS - 1);
    int tok = tokens[bs];
    int i2 = e >> 1;
    float div = expf(-(float)(2 * i2) * (logf(10000.0f) / (float)EE));
    float ang = (float)s * div;
    float pe = (e & 1) ? cosf(ang) : sinf(ang);
    x[bs * EE + e] = emb[tok * EE + e] + pe;
}

// ---------------------------------------------------------------------------
// Prep: transpose+convert weights to bf16.
// W1[l][NQ][F] -> W1T[l][F][NQ]; W2[l][F][E] -> W2T[l][E][F];
// Wc[l][E][E]  -> WcT[l][Eout][K].
// grid = L * 576 blocks (256 W1-tiles, 256 W2-tiles, 64 Wc-tiles), 256 thr.
// ---------------------------------------------------------------------------
__global__ __launch_bounds__(256) void k_trall(
        const float* __restrict__ W1, const float* __restrict__ W2,
        const float* __restrict__ Wc,
        short* __restrict__ W1T, short* __restrict__ W2T, short* __restrict__ WcT) {
    int bid = blockIdx.x;
    int lyr = bid / 576, rem = bid % 576;
    const float* in; short* out; int R, C, tile;
    if (rem < 256)      { in = W1 + (size_t)lyr*NQQ*FF; out = W1T + (size_t)lyr*FF*NQQ; R = NQQ; C = FF;  tile = rem; }
    else if (rem < 512) { in = W2 + (size_t)lyr*FF*EE;  out = W2T + (size_t)lyr*EE*FF;  R = FF;  C = EE;  tile = rem - 256; }
    else                { in = Wc + (size_t)lyr*EE*EE;  out = WcT + (size_t)lyr*EE*EE;  R = EE;  C = EE;  tile = rem - 512; }
    int tiles_c = C >> 5;
    int tc = tile % tiles_c, tr = tile / tiles_c;
    __shared__ float tl[32][33];
    int t = threadIdx.x;
    int rr = t >> 5, cc = t & 31;
    #pragma unroll
    for (int i = 0; i < 4; ++i)
        tl[rr + i*8][cc] = in[(size_t)(tr*32 + rr + i*8) * C + tc*32 + cc];
    __syncthreads();
    int ro = t >> 3, co = (t & 7) * 4;   // out row = orig col; 4 out cols
    s16x4 v;
    v[0] = f2bf(tl[co + 0][ro]);
    v[1] = f2bf(tl[co + 1][ro]);
    v[2] = f2bf(tl[co + 2][ro]);
    v[3] = f2bf(tl[co + 3][ro]);
    *(s16x4*)(out + (size_t)(tc*32 + ro) * R + tr*32 + co) = v;
}

// ---------------------------------------------------------------------------
// Kernel 2: quantum projection -> p (bf16) and p^T (bf16).
// p[b,s,e]; pT[b,e,s]. One thread per (b,s,h).
// ---------------------------------------------------------------------------
__global__ __launch_bounds__(256) void k_qproj2(
        const float* __restrict__ x, const float* __restrict__ theta,
        short* __restrict__ pbf, short* __restrict__ pbfT) {
    int idx = blockIdx.x * 256 + threadIdx.x;
    int h  = idx & (HH - 1);
    int bs = idx >> 3;
    int b  = bs >> 10, s = bs & (SS - 1);
    const float* xr = x + (size_t)bs * EE + h * DKK;
    const float* th = theta + h * DKK;
    float v[DKK];
    float cum = __cosf(xr[0] + th[0]);
    float prod1 = 1.0f;
    #pragma unroll
    for (int j = 1; j < DKK; ++j) {
        float c = __cosf(xr[j] + th[j]);
        cum *= c;
        prod1 *= c;
        v[j] = cum;
    }
    v[0] = prod1;
    short* pr = pbf + (size_t)bs * EE + h * DKK;
    #pragma unroll
    for (int j = 0; j < DKK; j += 2) {
        unsigned u = (unsigned)(unsigned short)f2bf(v[j]) |
                     ((unsigned)(unsigned short)f2bf(v[j + 1]) << 16);
        *(unsigned*)(pr + j) = u;
    }
    short* pT = pbfT + ((size_t)b * EE + h * DKK) * SS + s;
    #pragma unroll
    for (int j = 0; j < DKK; ++j)
        pT[(size_t)j * SS] = f2bf(v[j]);
}

// ---------------------------------------------------------------------------
// Kernel 3: flash attention, MFMA bf16. 1 wave/block, 16 queries/wave.
// grid = B * 64 = 512 blocks, 64 threads.
// scores: C[q][k]  A=P(q-rows, regs)  B=P(k-rows, global, NT-contiguous)
// PV:     C[q][e]  A=probs(LDS transpose)  B=P^T(e-rows, global)
// ---------------------------------------------------------------------------
__global__ __launch_bounds__(64) void k_attn3(const short* __restrict__ pbf,
                                              const short* __restrict__ pbfT,
                                              short* __restrict__ ybf) {
    const int b  = blockIdx.x >> 6;
    const int qt = blockIdx.x & 63;
    const int l  = threadIdx.x;
    const int lr = l & 15, lg = l >> 4;
    const int q0 = qt * 16;
    const short* pb  = pbf  + (size_t)b * SS * EE;
    const short* pbT = pbfT + (size_t)b * EE * SS;
    __shared__ short wlds[16 * 40];          // probs tile, stride 40 (80B, 2-way)

    short8 qf[8];
    #pragma unroll
    for (int kg = 0; kg < 8; ++kg)
        qf[kg] = *(const short8*)(pb + (size_t)(q0 + lr) * EE + kg * 32 + lg * 8);

    f32x4 acc[16];
    #pragma unroll
    for (int i = 0; i < 16; ++i) acc[i] = f32x4{0.f, 0.f, 0.f, 0.f};
    float m[4]  = {-1e30f, -1e30f, -1e30f, -1e30f};
    float ls[4] = {0.f, 0.f, 0.f, 0.f};
    const float scale = 0.17677669529663687f;   // 1/sqrt(32)

    for (int kt = 0; kt < SS / 32; ++kt) {
        f32x4 sc0 = {0.f,0.f,0.f,0.f}, sc1 = {0.f,0.f,0.f,0.f};
        #pragma unroll
        for (int kg = 0; kg < 8; ++kg) {
            short8 b0 = *(const short8*)(pb + (size_t)(kt*32 + lr)      * EE + kg*32 + lg*8);
            short8 b1 = *(const short8*)(pb + (size_t)(kt*32 + 16 + lr) * EE + kg*32 + lg*8);
            sc0 = mfma16(qf[kg], b0, sc0);
            sc1 = mfma16(qf[kg], b1, sc1);
        }
        #pragma unroll
        for (int r = 0; r < 4; ++r) {
            float s0 = sc0[r] * scale, s1 = sc1[r] * scale;
            float tm = fmaxf(s0, s1);
            tm = fmaxf(tm, __shfl_xor(tm, 1));
            tm = fmaxf(tm, __shfl_xor(tm, 2));
            tm = fmaxf(tm, __shfl_xor(tm, 4));
            tm = fmaxf(tm, __shfl_xor(tm, 8));
            float mn = fmaxf(m[r], tm);
            float rs = __expf(m[r] - mn);
            m[r] = mn;
            float p0 = __expf(s0 - mn), p1 = __expf(s1 - mn);
            float psum = p0 + p1;
            psum += __shfl_xor(psum, 1);
            psum += __shfl_xor(psum, 2);
            psum += __shfl_xor(psum, 4);
            psum += __shfl_xor(psum, 8);
            ls[r] = ls[r] * rs + psum;
            #pragma unroll
            for (int nt = 0; nt < 16; ++nt) acc[nt][r] *= rs;
            int q = lg * 4 + r;
            wlds[q * 40 + lr]      = f2bf(p0);
            wlds[q * 40 + 16 + lr] = f2bf(p1);
        }
        // same-wave LDS transpose read (compiler inserts lgkmcnt wait)
        short8 pa = *(const short8*)(wlds + lr * 40 + lg * 8);
        #pragma unroll
        for (int nt = 0; nt < 16; ++nt) {
            short8 bv = *(const short8*)(pbT + (size_t)(nt*16 + lr) * SS + kt*32 + lg*8);
            acc[nt] = mfma16(pa, bv, acc[nt]);
        }
    }

    #pragma unroll
    for (int r = 0; r < 4; ++r) {
        float inv = 1.0f / ls[r];
        int q = q0 + lg * 4 + r;
        #pragma unroll
        for (int nt = 0; nt < 16; ++nt)
            ybf[((size_t)b * SS + q) * EE + nt * 16 + lr] = f2bf(acc[nt][r] * inv);
    }
}

// ---------------------------------------------------------------------------
// Kernel 4: x = LN(x + y@Wc + bc). M=16 tokens/block, 4 waves split N=256.
// grid = 512 blocks, 256 threads.
// ---------------------------------------------------------------------------
__global__ __launch_bounds__(256) void k_wc3(
        const short* __restrict__ ybf, const short* __restrict__ WcT,
        const float* __restrict__ bc, const float* __restrict__ g,
        const float* __restrict__ bn, float* __restrict__ x) {
    const int t = threadIdx.x, w = t >> 6, l = t & 63;
    const int lr = l & 15, lg = l >> 4;
    const int tok0 = blockIdx.x * 16;
    __shared__ float outl[16 * 260];

    short8 af[8];
    #pragma unroll
    for (int kg = 0; kg < 8; ++kg)
        af[kg] = *(const short8*)(ybf + (size_t)(tok0 + lr) * EE + kg*32 + lg*8);

    f32x4 acc[4];
    #pragma unroll
    for (int i = 0; i < 4; ++i) acc[i] = f32x4{0.f,0.f,0.f,0.f};
    #pragma unroll
    for (int nt = 0; nt < 4; ++nt) {
        int e = w * 64 + nt * 16 + lr;
        #pragma unroll
        for (int kg = 0; kg < 8; ++kg) {
            short8 bv = *(const short8*)(WcT + (size_t)e * EE + kg*32 + lg*8);
            acc[nt] = mfma16(af[kg], bv, acc[nt]);
        }
    }
    #pragma unroll
    for (int nt = 0; nt < 4; ++nt) {
        int e = w * 64 + nt * 16 + lr;
        float bce = bc[e];
        #pragma unroll
        for (int r = 0; r < 4; ++r)
            outl[(lg*4 + r) * 260 + e] = acc[nt][r] + bce;
    }
    __syncthreads();
    #pragma unroll
    for (int j = 0; j < 4; ++j) {
        int q = w * 4 + j;
        float4 v  = *(float4*)&outl[q * 260 + l * 4];
        float4 xv = *(float4*)(x + (size_t)(tok0 + q) * EE + l * 4);
        v.x += xv.x; v.y += xv.y; v.z += xv.z; v.w += xv.w;
        float s = v.x + v.y + v.z + v.w;
        for (int off = 32; off > 0; off >>= 1) s += __shfl_xor(s, off);
        float mean = s * (1.0f / EE);
        float4 d;
        d.x = v.x - mean; d.y = v.y - mean; d.z = v.z - mean; d.w = v.w - mean;
        float s2 = d.x*d.x + d.y*d.y + d.z*d.z + d.w*d.w;
        for (int off = 32; off > 0; off >>= 1) s2 += __shfl_xor(s2, off);
        float inv = rsqrtf(s2 * (1.0f / EE) + 1e-5f);
        float4 gv  = *(const float4*)(g  + l * 4);
        float4 bnv = *(const float4*)(bn + l * 4);
        float4 o;
        o.x = d.x * inv * gv.x + bnv.x;
        o.y = d.y * inv * gv.y + bnv.y;
        o.z = d.z * inv * gv.z + bnv.z;
        o.w = d.w * inv * gv.w + bnv.w;
        *(float4*)(x + (size_t)(tok0 + q) * EE + l * 4) = o;
    }
}

// ---------------------------------------------------------------------------
// Kernel 5: FFN MFMA. M=16 tokens/block, 4 waves. GEMM1 N=1024 (wave:256),
// h in swizzled LDS bf16, GEMM2 N=256 (wave:64), fused LN epilogue.
// grid = 512 blocks, 256 threads.
// ---------------------------------------------------------------------------
__global__ __launch_bounds__(256) void k_ffn3(
        const float* __restrict__ theta, const short* __restrict__ W1T,
        const float* __restrict__ b1, const short* __restrict__ W2T,
        const float* __restrict__ b2, const float* __restrict__ g,
        const float* __restrict__ bn, float* __restrict__ x) {
    const int t = threadIdx.x, w = t >> 6, l = t & 63;
    const int lr = l & 15, lg = l >> 4;
    const int tok0 = blockIdx.x * 16;
    __shared__ short qls[16 * 256];      // swizzled bf16 [16][256]
    __shared__ short hls[16 * 1024];     // swizzled bf16 [16][1024]
    __shared__ float outl[16 * 260];

    {   // stage qv = cos(x)*cos(theta), bf16, swizzled
        int r = t >> 4, c0 = (t & 15) * 16;
        const float* xr = x + (size_t)(tok0 + r) * EE + c0;
        #pragma unroll
        for (int i = 0; i < 16; i += 2) {
            float v0 = __cosf(xr[i])     * __cosf(theta[c0 + i]);
            float v1 = __cosf(xr[i + 1]) * __cosf(theta[c0 + i + 1]);
            unsigned u = (unsigned)(unsigned short)f2bf(v0) |
                         ((unsigned)(unsigned short)f2bf(v1) << 16);
            int byte = (r * 512 + (c0 + i) * 2) ^ ((r & 7) << 4);
            *(unsigned*)((char*)qls + byte) = u;
        }
    }
    __syncthreads();

    short8 af[8];
    #pragma unroll
    for (int kg = 0; kg < 8; ++kg) {
        int byte = (lr * 512 + (kg*32 + lg*8) * 2) ^ ((lr & 7) << 4);
        af[kg] = *(const short8*)((char*)qls + byte);
    }

    // GEMM1: h[16][1024], wave slice N=256
    f32x4 a1[16];
    #pragma unroll
    for (int i = 0; i < 16; ++i) a1[i] = f32x4{0.f,0.f,0.f,0.f};
    #pragma unroll 4
    for (int nt = 0; nt < 16; ++nt) {
        int f = w * 256 + nt * 16 + lr;
        #pragma unroll
        for (int kg = 0; kg < 8; ++kg) {
            short8 bv = *(const short8*)(W1T + (size_t)f * NQQ + kg*32 + lg*8);
            a1[nt] = mfma16(af[kg], bv, a1[nt]);
        }
    }
    #pragma unroll
    for (int nt = 0; nt < 16; ++nt) {
        int f = w * 256 + nt * 16 + lr;
        float bb = b1[f];
        #pragma unroll
        for (int r = 0; r < 4; ++r) {
            int q = lg * 4 + r;
            float hv = fmaxf(a1[nt][r] + bb, 0.0f);
            int byte = (q * 2048 + f * 2) ^ ((q & 7) << 4);
            *(short*)((char*)hls + byte) = f2bf(hv);
        }
    }
    __syncthreads();

    // GEMM2: out[16][256], wave slice N=64, K=1024
    f32x4 a2[4];
    #pragma unroll
    for (int i = 0; i < 4; ++i) a2[i] = f32x4{0.f,0.f,0.f,0.f};
    #pragma unroll 4
    for (int kg = 0; kg < 32; ++kg) {
        int byte = (lr * 2048 + (kg*32 + lg*8) * 2) ^ ((lr & 7) << 4);
        short8 hf = *(const short8*)((char*)hls + byte);
        #pragma unroll
        for (int nt = 0; nt < 4; ++nt) {
            int e = w * 64 + nt * 16 + lr;
            short8 bv = *(const short8*)(W2T + (size_t)e * FF + kg*32 + lg*8);
            a2[nt] = mfma16(hf, bv, a2[nt]);
        }
    }
    #pragma unroll
    for (int nt = 0; nt < 4; ++nt) {
        int e = w * 64 + nt * 16 + lr;
        float b2e = b2[e];
        #pragma unroll
        for (int r = 0; r < 4; ++r)
            outl[(lg*4 + r) * 260 + e] = a2[nt][r] + b2e;
    }
    __syncthreads();
    #pragma unroll
    for (int j = 0; j < 4; ++j) {
        int q = w * 4 + j;
        float4 v  = *(float4*)&outl[q * 260 + l * 4];
        float4 xv = *(float4*)(x + (size_t)(tok0 + q) * EE + l * 4);
        v.x += xv.x; v.y += xv.y; v.z += xv.z; v.w += xv.w;
        float s = v.x + v.y + v.z + v.w;
        for (int off = 32; off > 0; off >>= 1) s += __shfl_xor(s, off);
        float mean = s * (1.0f / EE);
        float4 d;
        d.x = v.x - mean; d.y = v.y - mean; d.z = v.z - mean; d.w = v.w - mean;
        float s2 = d.x*d.x + d.y*d.y + d.z*d.z + d.w*d.w;
        for (int off = 32; off > 0; off >>= 1) s2 += __shfl_xor(s2, off);
        float inv = rsqrtf(s2 * (1.0f / EE) + 1e-5f);
        float4 gv  = *(const float4*)(g  + l * 4);
        float4 bnv = *(const float4*)(bn + l * 4);
        float4 o;
        o.x = d.x * inv * gv.x + bnv.x;
        o.y = d.y * inv * gv.y + bnv.y;
        o.z = d.z * inv * gv.z + bnv.z;
        o.w = d.w * inv * gv.w + bnv.w;
        *(float4*)(x + (size_t)(tok0 + q) * EE + l * 4) = o;
    }
}

// ---------------------------------------------------------------------------
// Kernel 6: classifier head
// ---------------------------------------------------------------------------
__global__ void k_head(const float* __restrict__ x,
                       const float* __restrict__ Wcls,
                       const float* __restrict__ bcls,
                       float* __restrict__ out) {
    int b = blockIdx.x;
    int t = threadIdx.x;
    __shared__ float xm[EE];
    float acc = 0.0f;
    for (int s = 0; s < SS; ++s) acc += x[(size_t)(b * SS + s) * EE + t];
    xm[t] = acc * (1.0f / (float)SS);
    __syncthreads();
    if (t < CC) {
        float a = bcls[t];
        #pragma unroll 8
        for (int e = 0; e < EE; ++e) a += xm[e] * Wcls[e * CC + t];
        out[b * CC + t] = a;
    }
}

// ---------------------------------------------------------------------------
extern "C" void kernel_launch(void* const* d_in, const int* in_sizes, int n_in,
                              void* d_out, int out_size, void* d_ws, size_t ws_size,
                              hipStream_t stream) {
    (void)in_sizes; (void)n_in; (void)out_size; (void)ws_size;
    const int*   tokens     = (const int*)d_in[0];
    const float* emb        = (const float*)d_in[1];
    const float* theta_attn = (const float*)d_in[2];
    const float* Wc         = (const float*)d_in[3];
    const float* bc         = (const float*)d_in[4];
    const float* g1         = (const float*)d_in[5];
    const float* bn1        = (const float*)d_in[6];
    const float* theta_ffn  = (const float*)d_in[7];
    const float* W1         = (const float*)d_in[8];
    const float* b1         = (const float*)d_in[9];
    const float* W2         = (const float*)d_in[10];
    const float* b2         = (const float*)d_in[11];
    const float* g2         = (const float*)d_in[12];
    const float* bn2        = (const float*)d_in[13];
    const float* Wcls       = (const float*)d_in[14];
    const float* bcls       = (const float*)d_in[15];
    float* out = (float*)d_out;

    const size_t nTok = (size_t)BB * SS * EE;     // 2M
    float* x    = (float*)d_ws;                   // 8 MB
    short* pbf  = (short*)(x + nTok);             // 4 MB
    short* pbfT = pbf  + nTok;                    // 4 MB
    short* ybf  = pbfT + nTok;                    // 4 MB
    short* W1T  = ybf  + nTok;                    // L*F*NQ bf16 = 2 MB
    short* W2T  = W1T + (size_t)LL * FF * NQQ;    // 2 MB
    short* WcT  = W2T + (size_t)LL * EE * FF;     // 0.5 MB

    k_embed<<<BB * SS, EE, 0, stream>>>(tokens, emb, x);
    k_trall<<<LL * 576, 256, 0, stream>>>(W1, W2, Wc, W1T, W2T, WcT);

    for (int l = 0; l < LL; ++l) {
        k_qproj2<<<(BB * SS * HH) / 256, 256, 0, stream>>>(
            x, theta_attn + (size_t)l * HH * DKK, pbf, pbfT);
        k_attn3<<<BB * 64, 64, 0, stream>>>(pbf, pbfT, ybf);
        k_wc3<<<(BB * SS) / 16, 256, 0, stream>>>(
            ybf, WcT + (size_t)l * EE * EE, bc + (size_t)l * EE,
            g1 + (size_t)l * EE, bn1 + (size_t)l * EE, x);
        k_ffn3<<<(BB * SS) / 16, 256, 0, stream>>>(
            theta_ffn + (size_t)l * NQQ,
            W1T + (size_t)l * FF * NQQ, b1 + (size_t)l * FF,
            W2T + (size_t)l * EE * FF, b2 + (size_t)l * EE,
            g2 + (size_t)l * EE, bn2 + (size_t)l * EE, x);
    }

    k_head<<<BB, 256, 0, stream>>>(x, Wcls, bcls, out);
}

// Round 4
// 677.466 us; speedup vs baseline: 11.1545x; 1.2189x over previous
//
#include <hip/hip_runtime.h>
#include <hip/hip_bf16.h>
#include <math.h>

#define BB 8
#define SS 1024
#define EE 256
#define HH 8
#define DKK 32
#define LL 4
#define FF 1024
#define NQQ 256
#define CC 10

typedef __attribute__((ext_vector_type(8))) short short8;
typedef __attribute__((ext_vector_type(4))) short s16x4;
typedef __attribute__((ext_vector_type(4))) float f32x4;

static __device__ __forceinline__ f32x4 mfma16(short8 a, short8 b, f32x4 c) {
    return __builtin_amdgcn_mfma_f32_16x16x32_bf16(a, b, c, 0, 0, 0);
}
static __device__ __forceinline__ short f2bf(float f) {
    __hip_bfloat16 h = __float2bfloat16(f);
    return *reinterpret_cast<short*>(&h);
}

// ---------------------------------------------------------------------------
// Kernel 1: x[b,s,e] = emb[tokens[b,s], e] + pos_encoding(s, e)  (fp32, exact)
// ---------------------------------------------------------------------------
__global__ void k_embed(const int* __restrict__ tokens,
                        const float* __restrict__ emb,
                        float* __restrict__ x) {
    int bs = blockIdx.x;
    int e  = threadIdx.x;
    int s  = bs & (SS - 1);
    int tok = tokens[bs];
    int i2 = e >> 1;
    float div = expf(-(float)(2 * i2) * (logf(10000.0f) / (float)EE));
    float ang = (float)s * div;
    float pe = (e & 1) ? cosf(ang) : sinf(ang);
    x[bs * EE + e] = emb[tok * EE + e] + pe;
}

// ---------------------------------------------------------------------------
// Prep: transpose+convert weights to bf16 (W1T, W2T, WcT). Unchanged.
// ---------------------------------------------------------------------------
__global__ __launch_bounds__(256) void k_trall(
        const float* __restrict__ W1, const float* __restrict__ W2,
        const float* __restrict__ Wc,
        short* __restrict__ W1T, short* __restrict__ W2T, short* __restrict__ WcT) {
    int bid = blockIdx.x;
    int lyr = bid / 576, rem = bid % 576;
    const float* in; short* out; int R, C, tile;
    if (rem < 256)      { in = W1 + (size_t)lyr*NQQ*FF; out = W1T + (size_t)lyr*FF*NQQ; R = NQQ; C = FF;  tile = rem; }
    else if (rem < 512) { in = W2 + (size_t)lyr*FF*EE;  out = W2T + (size_t)lyr*EE*FF;  R = FF;  C = EE;  tile = rem - 256; }
    else                { in = Wc + (size_t)lyr*EE*EE;  out = WcT + (size_t)lyr*EE*EE;  R = EE;  C = EE;  tile = rem - 512; }
    int tiles_c = C >> 5;
    int tc = tile % tiles_c, tr = tile / tiles_c;
    __shared__ float tl[32][33];
    int t = threadIdx.x;
    int rr = t >> 5, cc = t & 31;
    #pragma unroll
    for (int i = 0; i < 4; ++i)
        tl[rr + i*8][cc] = in[(size_t)(tr*32 + rr + i*8) * C + tc*32 + cc];
    __syncthreads();
    int ro = t >> 3, co = (t & 7) * 4;
    s16x4 v;
    v[0] = f2bf(tl[co + 0][ro]);
    v[1] = f2bf(tl[co + 1][ro]);
    v[2] = f2bf(tl[co + 2][ro]);
    v[3] = f2bf(tl[co + 3][ro]);
    *(s16x4*)(out + (size_t)(tc*32 + ro) * R + tr*32 + co) = v;
}

// ---------------------------------------------------------------------------
// Kernel 2: quantum projection -> p (bf16) and p^T (bf16). Unchanged.
// ---------------------------------------------------------------------------
__global__ __launch_bounds__(256) void k_qproj2(
        const float* __restrict__ x, const float* __restrict__ theta,
        short* __restrict__ pbf, short* __restrict__ pbfT) {
    int idx = blockIdx.x * 256 + threadIdx.x;
    int h  = idx & (HH - 1);
    int bs = idx >> 3;
    int b  = bs >> 10, s = bs & (SS - 1);
    const float* xr = x + (size_t)bs * EE + h * DKK;
    const float* th = theta + h * DKK;
    float v[DKK];
    float cum = __cosf(xr[0] + th[0]);
    float prod1 = 1.0f;
    #pragma unroll
    for (int j = 1; j < DKK; ++j) {
        float c = __cosf(xr[j] + th[j]);
        cum *= c;
        prod1 *= c;
        v[j] = cum;
    }
    v[0] = prod1;
    short* pr = pbf + (size_t)bs * EE + h * DKK;
    #pragma unroll
    for (int j = 0; j < DKK; j += 2) {
        unsigned u = (unsigned)(unsigned short)f2bf(v[j]) |
                     ((unsigned)(unsigned short)f2bf(v[j + 1]) << 16);
        *(unsigned*)(pr + j) = u;
    }
    short* pT = pbfT + ((size_t)b * EE + h * DKK) * SS + s;
    #pragma unroll
    for (int j = 0; j < DKK; ++j)
        pT[(size_t)j * SS] = f2bf(v[j]);
}

// ---------------------------------------------------------------------------
// Kernel 3: flash attention, MFMA bf16, KV-split over 4 waves.
// grid = B * 64 = 512 blocks, 256 threads (4 waves).
// Each wave: 16 queries (same per block), K-tiles kt = w + 4*i, i=0..7,
// private online-softmax state; LDS merge at the end.
// ---------------------------------------------------------------------------
__global__ __launch_bounds__(256) void k_attn4(const short* __restrict__ pbf,
                                               const short* __restrict__ pbfT,
                                               short* __restrict__ ybf) {
    const int b   = blockIdx.x >> 6;
    const int qt  = blockIdx.x & 63;
    const int tid = threadIdx.x;
    const int w   = tid >> 6;
    const int l   = tid & 63;
    const int lr  = l & 15, lg = l >> 4;
    const int q0  = qt * 16;
    const short* pb  = pbf  + (size_t)b * SS * EE;
    const short* pbT = pbfT + (size_t)b * EE * SS;

    __shared__ float accL[4][16][264];   // stride 264: 2-way scatter (free)
    __shared__ float mL[4][16];
    __shared__ float lsL[4][16];
    __shared__ short wlds[4][16 * 40];

    short8 qf[8];
    #pragma unroll
    for (int kg = 0; kg < 8; ++kg)
        qf[kg] = *(const short8*)(pb + (size_t)(q0 + lr) * EE + kg * 32 + lg * 8);

    f32x4 acc[16];
    #pragma unroll
    for (int i = 0; i < 16; ++i) acc[i] = f32x4{0.f, 0.f, 0.f, 0.f};
    float m[4]  = {-1e30f, -1e30f, -1e30f, -1e30f};
    float ls[4] = {0.f, 0.f, 0.f, 0.f};
    const float scale = 0.17677669529663687f;   // 1/sqrt(32)
    short* wl = wlds[w];

    for (int i = 0; i < 8; ++i) {
        const int kt = w + 4 * i;
        // batch-issue the 16 score B-fragment loads (single latency exposure)
        short8 sb0[8], sb1[8];
        #pragma unroll
        for (int kg = 0; kg < 8; ++kg) {
            sb0[kg] = *(const short8*)(pb + (size_t)(kt*32 + lr)      * EE + kg*32 + lg*8);
            sb1[kg] = *(const short8*)(pb + (size_t)(kt*32 + 16 + lr) * EE + kg*32 + lg*8);
        }
        f32x4 sc0 = {0.f,0.f,0.f,0.f}, sc1 = {0.f,0.f,0.f,0.f};
        #pragma unroll
        for (int kg = 0; kg < 8; ++kg) {
            sc0 = mfma16(qf[kg], sb0[kg], sc0);
            sc1 = mfma16(qf[kg], sb1[kg], sc1);
        }
        // issue PV B-fragment loads before softmax so they overlap VALU work
        short8 pvb[16];
        #pragma unroll
        for (int nt = 0; nt < 16; ++nt)
            pvb[nt] = *(const short8*)(pbT + (size_t)(nt*16 + lr) * SS + kt*32 + lg*8);

        #pragma unroll
        for (int r = 0; r < 4; ++r) {
            float s0 = sc0[r] * scale, s1 = sc1[r] * scale;
            float tm = fmaxf(s0, s1);
            tm = fmaxf(tm, __shfl_xor(tm, 1));
            tm = fmaxf(tm, __shfl_xor(tm, 2));
            tm = fmaxf(tm, __shfl_xor(tm, 4));
            tm = fmaxf(tm, __shfl_xor(tm, 8));
            float mn = fmaxf(m[r], tm);
            float rs = __expf(m[r] - mn);
            m[r] = mn;
            float p0 = __expf(s0 - mn), p1 = __expf(s1 - mn);
            float psum = p0 + p1;
            psum += __shfl_xor(psum, 1);
            psum += __shfl_xor(psum, 2);
            psum += __shfl_xor(psum, 4);
            psum += __shfl_xor(psum, 8);
            ls[r] = ls[r] * rs + psum;
            #pragma unroll
            for (int nt = 0; nt < 16; ++nt) acc[nt][r] *= rs;
            int q = lg * 4 + r;
            wl[q * 40 + lr]      = f2bf(p0);
            wl[q * 40 + 16 + lr] = f2bf(p1);
        }
        short8 pa = *(const short8*)(wl + lr * 40 + lg * 8);
        #pragma unroll
        for (int nt = 0; nt < 16; ++nt)
            acc[nt] = mfma16(pa, pvb[nt], acc[nt]);
    }

    // dump per-wave state to LDS
    #pragma unroll
    for (int nt = 0; nt < 16; ++nt)
        #pragma unroll
        for (int r = 0; r < 4; ++r)
            accL[w][lg * 4 + r][nt * 16 + lr] = acc[nt][r];
    if (lr == 0) {
        #pragma unroll
        for (int r = 0; r < 4; ++r) {
            mL[w][lg * 4 + r]  = m[r];
            lsL[w][lg * 4 + r] = ls[r];
        }
    }
    __syncthreads();

    // merge: thread -> (q = tid>>4, cols c*16..c*16+15)
    const int q = tid >> 4, c = tid & 15;
    float M = fmaxf(fmaxf(mL[0][q], mL[1][q]), fmaxf(mL[2][q], mL[3][q]));
    float sc[4], L = 0.f;
    #pragma unroll
    for (int w2 = 0; w2 < 4; ++w2) {
        sc[w2] = __expf(mL[w2][q] - M);
        L += lsL[w2][q] * sc[w2];
    }
    float inv = 1.0f / L;
    short ov[16];
    #pragma unroll
    for (int j = 0; j < 4; ++j) {
        float4 v = {0.f, 0.f, 0.f, 0.f};
        #pragma unroll
        for (int w2 = 0; w2 < 4; ++w2) {
            float4 a = *(const float4*)&accL[w2][q][c * 16 + j * 4];
            v.x += a.x * sc[w2]; v.y += a.y * sc[w2];
            v.z += a.z * sc[w2]; v.w += a.w * sc[w2];
        }
        ov[j*4 + 0] = f2bf(v.x * inv);
        ov[j*4 + 1] = f2bf(v.y * inv);
        ov[j*4 + 2] = f2bf(v.z * inv);
        ov[j*4 + 3] = f2bf(v.w * inv);
    }
    short* yr = ybf + ((size_t)b * SS + q0 + q) * EE + c * 16;
    *(short8*)yr       = *(const short8*)&ov[0];
    *(short8*)(yr + 8) = *(const short8*)&ov[8];
}

// ---------------------------------------------------------------------------
// Kernel 4: x = LN(x + y@Wc + bc). Unchanged.
// ---------------------------------------------------------------------------
__global__ __launch_bounds__(256) void k_wc3(
        const short* __restrict__ ybf, const short* __restrict__ WcT,
        const float* __restrict__ bc, const float* __restrict__ g,
        const float* __restrict__ bn, float* __restrict__ x) {
    const int t = threadIdx.x, w = t >> 6, l = t & 63;
    const int lr = l & 15, lg = l >> 4;
    const int tok0 = blockIdx.x * 16;
    __shared__ float outl[16 * 260];

    short8 af[8];
    #pragma unroll
    for (int kg = 0; kg < 8; ++kg)
        af[kg] = *(const short8*)(ybf + (size_t)(tok0 + lr) * EE + kg*32 + lg*8);

    f32x4 acc[4];
    #pragma unroll
    for (int i = 0; i < 4; ++i) acc[i] = f32x4{0.f,0.f,0.f,0.f};
    #pragma unroll
    for (int nt = 0; nt < 4; ++nt) {
        int e = w * 64 + nt * 16 + lr;
        #pragma unroll
        for (int kg = 0; kg < 8; ++kg) {
            short8 bv = *(const short8*)(WcT + (size_t)e * EE + kg*32 + lg*8);
            acc[nt] = mfma16(af[kg], bv, acc[nt]);
        }
    }
    #pragma unroll
    for (int nt = 0; nt < 4; ++nt) {
        int e = w * 64 + nt * 16 + lr;
        float bce = bc[e];
        #pragma unroll
        for (int r = 0; r < 4; ++r)
            outl[(lg*4 + r) * 260 + e] = acc[nt][r] + bce;
    }
    __syncthreads();
    #pragma unroll
    for (int j = 0; j < 4; ++j) {
        int q = w * 4 + j;
        float4 v  = *(float4*)&outl[q * 260 + l * 4];
        float4 xv = *(float4*)(x + (size_t)(tok0 + q) * EE + l * 4);
        v.x += xv.x; v.y += xv.y; v.z += xv.z; v.w += xv.w;
        float s = v.x + v.y + v.z + v.w;
        for (int off = 32; off > 0; off >>= 1) s += __shfl_xor(s, off);
        float mean = s * (1.0f / EE);
        float4 d;
        d.x = v.x - mean; d.y = v.y - mean; d.z = v.z - mean; d.w = v.w - mean;
        float s2 = d.x*d.x + d.y*d.y + d.z*d.z + d.w*d.w;
        for (int off = 32; off > 0; off >>= 1) s2 += __shfl_xor(s2, off);
        float inv = rsqrtf(s2 * (1.0f / EE) + 1e-5f);
        float4 gv  = *(const float4*)(g  + l * 4);
        float4 bnv = *(const float4*)(bn + l * 4);
        float4 o;
        o.x = d.x * inv * gv.x + bnv.x;
        o.y = d.y * inv * gv.y + bnv.y;
        o.z = d.z * inv * gv.z + bnv.z;
        o.w = d.w * inv * gv.w + bnv.w;
        *(float4*)(x + (size_t)(tok0 + q) * EE + l * 4) = o;
    }
}

// ---------------------------------------------------------------------------
// Kernel 5: FFN MFMA. Unchanged.
// ---------------------------------------------------------------------------
__global__ __launch_bounds__(256) void k_ffn3(
        const float* __restrict__ theta, const short* __restrict__ W1T,
        const float* __restrict__ b1, const short* __restrict__ W2T,
        const float* __restrict__ b2, const float* __restrict__ g,
        const float* __restrict__ bn, float* __restrict__ x) {
    const int t = threadIdx.x, w = t >> 6, l = t & 63;
    const int lr = l & 15, lg = l >> 4;
    const int tok0 = blockIdx.x * 16;
    __shared__ short qls[16 * 256];
    __shared__ short hls[16 * 1024];
    __shared__ float outl[16 * 260];

    {
        int r = t >> 4, c0 = (t & 15) * 16;
        const float* xr = x + (size_t)(tok0 + r) * EE + c0;
        #pragma unroll
        for (int i = 0; i < 16; i += 2) {
            float v0 = __cosf(xr[i])     * __cosf(theta[c0 + i]);
            float v1 = __cosf(xr[i + 1]) * __cosf(theta[c0 + i + 1]);
            unsigned u = (unsigned)(unsigned short)f2bf(v0) |
                         ((unsigned)(unsigned short)f2bf(v1) << 16);
            int byte = (r * 512 + (c0 + i) * 2) ^ ((r & 7) << 4);
            *(unsigned*)((char*)qls + byte) = u;
        }
    }
    __syncthreads();

    short8 af[8];
    #pragma unroll
    for (int kg = 0; kg < 8; ++kg) {
        int byte = (lr * 512 + (kg*32 + lg*8) * 2) ^ ((lr & 7) << 4);
        af[kg] = *(const short8*)((char*)qls + byte);
    }

    f32x4 a1[16];
    #pragma unroll
    for (int i = 0; i < 16; ++i) a1[i] = f32x4{0.f,0.f,0.f,0.f};
    #pragma unroll 4
    for (int nt = 0; nt < 16; ++nt) {
        int f = w * 256 + nt * 16 + lr;
        #pragma unroll
        for (int kg = 0; kg < 8; ++kg) {
            short8 bv = *(const short8*)(W1T + (size_t)f * NQQ + kg*32 + lg*8);
            a1[nt] = mfma16(af[kg], bv, a1[nt]);
        }
    }
    #pragma unroll
    for (int nt = 0; nt < 16; ++nt) {
        int f = w * 256 + nt * 16 + lr;
        float bb = b1[f];
        #pragma unroll
        for (int r = 0; r < 4; ++r) {
            int q = lg * 4 + r;
            float hv = fmaxf(a1[nt][r] + bb, 0.0f);
            int byte = (q * 2048 + f * 2) ^ ((q & 7) << 4);
            *(short*)((char*)hls + byte) = f2bf(hv);
        }
    }
    __syncthreads();

    f32x4 a2[4];
    #pragma unroll
    for (int i = 0; i < 4; ++i) a2[i] = f32x4{0.f,0.f,0.f,0.f};
    #pragma unroll 4
    for (int kg = 0; kg < 32; ++kg) {
        int byte = (lr * 2048 + (kg*32 + lg*8) * 2) ^ ((lr & 7) << 4);
        short8 hf = *(const short8*)((char*)hls + byte);
        #pragma unroll
        for (int nt = 0; nt < 4; ++nt) {
            int e = w * 64 + nt * 16 + lr;
            short8 bv = *(const short8*)(W2T + (size_t)e * FF + kg*32 + lg*8);
            a2[nt] = mfma16(hf, bv, a2[nt]);
        }
    }
    #pragma unroll
    for (int nt = 0; nt < 4; ++nt) {
        int e = w * 64 + nt * 16 + lr;
        float b2e = b2[e];
        #pragma unroll
        for (int r = 0; r < 4; ++r)
            outl[(lg*4 + r) * 260 + e] = a2[nt][r] + b2e;
    }
    __syncthreads();
    #pragma unroll
    for (int j = 0; j < 4; ++j) {
        int q = w * 4 + j;
        float4 v  = *(float4*)&outl[q * 260 + l * 4];
        float4 xv = *(float4*)(x + (size_t)(tok0 + q) * EE + l * 4);
        v.x += xv.x; v.y += xv.y; v.z += xv.z; v.w += xv.w;
        float s = v.x + v.y + v.z + v.w;
        for (int off = 32; off > 0; off >>= 1) s += __shfl_xor(s, off);
        float mean = s * (1.0f / EE);
        float4 d;
        d.x = v.x - mean; d.y = v.y - mean; d.z = v.z - mean; d.w = v.w - mean;
        float s2 = d.x*d.x + d.y*d.y + d.z*d.z + d.w*d.w;
        for (int off = 32; off > 0; off >>= 1) s2 += __shfl_xor(s2, off);
        float inv = rsqrtf(s2 * (1.0f / EE) + 1e-5f);
        float4 gv  = *(const float4*)(g  + l * 4);
        float4 bnv = *(const float4*)(bn + l * 4);
        float4 o;
        o.x = d.x * inv * gv.x + bnv.x;
        o.y = d.y * inv * gv.y + bnv.y;
        o.z = d.z * inv * gv.z + bnv.z;
        o.w = d.w * inv * gv.w + bnv.w;
        *(float4*)(x + (size_t)(tok0 + q) * EE + l * 4) = o;
    }
}

// ---------------------------------------------------------------------------
// Kernel 6: classifier head
// ---------------------------------------------------------------------------
__global__ void k_head(const float* __restrict__ x,
                       const float* __restrict__ Wcls,
                       const float* __restrict__ bcls,
                       float* __restrict__ out) {
    int b = blockIdx.x;
    int t = threadIdx.x;
    __shared__ float xm[EE];
    float acc = 0.0f;
    for (int s = 0; s < SS; ++s) acc += x[(size_t)(b * SS + s) * EE + t];
    xm[t] = acc * (1.0f / (float)SS);
    __syncthreads();
    if (t < CC) {
        float a = bcls[t];
        #pragma unroll 8
        for (int e = 0; e < EE; ++e) a += xm[e] * Wcls[e * CC + t];
        out[b * CC + t] = a;
    }
}

// ---------------------------------------------------------------------------
extern "C" void kernel_launch(void* const* d_in, const int* in_sizes, int n_in,
                              void* d_out, int out_size, void* d_ws, size_t ws_size,
                              hipStream_t stream) {
    (void)in_sizes; (void)n_in; (void)out_size; (void)ws_size;
    const int*   tokens     = (const int*)d_in[0];
    const float* emb        = (const float*)d_in[1];
    const float* theta_attn = (const float*)d_in[2];
    const float* Wc         = (const float*)d_in[3];
    const float* bc         = (const float*)d_in[4];
    const float* g1         = (const float*)d_in[5];
    const float* bn1        = (const float*)d_in[6];
    const float* theta_ffn  = (const float*)d_in[7];
    const float* W1         = (const float*)d_in[8];
    const float* b1         = (const float*)d_in[9];
    const float* W2         = (const float*)d_in[10];
    const float* b2         = (const float*)d_in[11];
    const float* g2         = (const float*)d_in[12];
    const float* bn2        = (const float*)d_in[13];
    const float* Wcls       = (const float*)d_in[14];
    const float* bcls       = (const float*)d_in[15];
    float* out = (float*)d_out;

    const size_t nTok = (size_t)BB * SS * EE;     // 2M
    float* x    = (float*)d_ws;                   // 8 MB
    short* pbf  = (short*)(x + nTok);             // 4 MB
    short* pbfT = pbf  + nTok;                    // 4 MB
    short* ybf  = pbfT + nTok;                    // 4 MB
    short* W1T  = ybf  + nTok;                    // 2 MB
    short* W2T  = W1T + (size_t)LL * FF * NQQ;    // 2 MB
    short* WcT  = W2T + (size_t)LL * EE * FF;     // 0.5 MB

    k_embed<<<BB * SS, EE, 0, stream>>>(tokens, emb, x);
    k_trall<<<LL * 576, 256, 0, stream>>>(W1, W2, Wc, W1T, W2T, WcT);

    for (int l = 0; l < LL; ++l) {
        k_qproj2<<<(BB * SS * HH) / 256, 256, 0, stream>>>(
            x, theta_attn + (size_t)l * HH * DKK, pbf, pbfT);
        k_attn4<<<BB * 64, 256, 0, stream>>>(pbf, pbfT, ybf);
        k_wc3<<<(BB * SS) / 16, 256, 0, stream>>>(
            ybf, WcT + (size_t)l * EE * EE, bc + (size_t)l * EE,
            g1 + (size_t)l * EE, bn1 + (size_t)l * EE, x);
        k_ffn3<<<(BB * SS) / 16, 256, 0, stream>>>(
            theta_ffn + (size_t)l * NQQ,
            W1T + (size_t)l * FF * NQQ, b1 + (size_t)l * FF,
            W2T + (size_t)l * EE * FF, b2 + (size_t)l * EE,
            g2 + (size_t)l * EE, bn2 + (size_t)l * EE, x);
    }

    k_head<<<BB, 256, 0, stream>>>(x, Wcls, bcls, out);
}